// Round 5
// baseline (198.136 us; speedup 1.0000x reference)
//
#include <hip/hip_runtime.h>
#include <math.h>
#include <stddef.h>

#define N224 224
#define PIX 50176      // 224*224
#define ROWS113 25312  // 113*224, Cx/Sx rows per image

// ---- ws float offsets ----
#define OFF_SX    1214976
#define OFF_SPEC  4816896
#define OFF_WT    3211264              // right after h1 (16*16*112*112)
#define OFF_WT2   (OFF_WT + 18432)
#define OFF_WT1   (OFF_WT + 23040)
#define OFF_SU3   (OFF_WT + 23472)    // [64 s][64 u]
#define OFF_SU2   (OFF_WT + 23600)    // [32 s][32 u]
#define OFF_SU1   (OFF_WT + 23664)    // [16 s][16 u]
#define OFF_PART  (OFF_WT + 32768)    // 16*64*112 = 114688 floats

// ---------------- prep: weight transpose + BN fold --------------------------
__global__ __launch_bounds__(256) void prep(
    const float* __restrict__ c1w, const float* __restrict__ c2w,
    const float* __restrict__ c3w, const float* __restrict__ c1b,
    const float* __restrict__ c2b, const float* __restrict__ c3b,
    const float* __restrict__ g1, const float* __restrict__ be1,
    const float* __restrict__ m1, const float* __restrict__ v1,
    const float* __restrict__ g2, const float* __restrict__ be2,
    const float* __restrict__ m2, const float* __restrict__ v2,
    const float* __restrict__ g3, const float* __restrict__ be3,
    const float* __restrict__ m3, const float* __restrict__ v3,
    float* __restrict__ wt3, float* __restrict__ wt2, float* __restrict__ wt1,
    float* __restrict__ su3, float* __restrict__ su2, float* __restrict__ su1)
{
  const int idx = blockIdx.x * 256 + threadIdx.x;
  const int stride = gridDim.x * 256;
  for (int i = idx; i < 18432; i += stride) {          // wT3[(cc*9+k)*64+co]
    const int co = i & 63, k = (i >> 6) % 9, cc = i / 576;
    wt3[i] = c3w[co*288 + cc*9 + k];
  }
  for (int i = idx; i < 4608; i += stride) {           // wT2[(cc*9+k)*32+co]
    const int co = i & 31, k = (i >> 5) % 9, cc = i / 288;
    wt2[i] = c2w[co*144 + cc*9 + k];
  }
  for (int i = idx; i < 432; i += stride) {            // wT1[(cc*9+k)*16+co]
    const int co = i & 15, k = (i >> 4) % 9, cc = i / 144;
    wt1[i] = c1w[co*27 + cc*9 + k];
  }
  if (idx < 64) {
    const float s = g3[idx] * rsqrtf(v3[idx] + 1e-5f);
    su3[idx] = s; su3[64+idx] = (c3b[idx] - m3[idx]) * s + be3[idx];
  } else if (idx < 96) {
    const int c = idx - 64;
    const float s = g2[c] * rsqrtf(v2[c] + 1e-5f);
    su2[c] = s; su2[32+c] = (c2b[c] - m2[c]) * s + be2[c];
  } else if (idx < 112) {
    const int c = idx - 96;
    const float s = g1[c] * rsqrtf(v1[c] + 1e-5f);
    su1[c] = s; su1[16+c] = (c1b[c] - m1[c]) * s + be1[c];
  }
}

// ---------------- DFT stage 1 (half rows): Cx = C @ x, Sx = S @ x -----------
__global__ __launch_bounds__(64) void dft1(
    const float* __restrict__ seq, const float* __restrict__ Cm,
    const float* __restrict__ Sm, float* __restrict__ Cx, float* __restrict__ Sx)
{
  const int p = blockIdx.z;
  const int b = p / 3, ch = p % 3;
  const float* __restrict__ x = seq + ((((size_t)b * 8 + 4) * 3 + ch) * PIX);
  const int i0 = blockIdx.y * 32;
  const int k0 = blockIdx.x * 32;
  const int tid = threadIdx.x;
  const int tx = tid & 7, ty = tid >> 3;
  __shared__ float Ctt[16][36], Stt[16][36], Xt[16][36];
  float aC[4][4], aS[4][4];
#pragma unroll
  for (int a = 0; a < 4; ++a)
#pragma unroll
    for (int d = 0; d < 4; ++d) { aC[a][d] = 0.f; aS[a][d] = 0.f; }

  const int sr = tid >> 1;
  const int sk = (tid & 1) * 8;
  const int xj = tid >> 2;
  const int xk = (tid & 3) * 8;

  const float* xbase = x  + (size_t)xj * N224 + k0 + xk;
  const float* cbase = Cm + (size_t)(i0 + sr) * N224 + sk;
  const float* sbase = Sm + (size_t)(i0 + sr) * N224 + sk;

  float4 rx0 = *(const float4*)(xbase);
  float4 rx1 = *(const float4*)(xbase + 4);
  float4 rc0 = *(const float4*)(cbase);
  float4 rc1 = *(const float4*)(cbase + 4);
  float4 rs0 = *(const float4*)(sbase);
  float4 rs1 = *(const float4*)(sbase + 4);

  for (int jt = 0; jt < 14; ++jt) {
    __syncthreads();
    *(float4*)&Xt[xj][xk]     = rx0;
    *(float4*)&Xt[xj][xk + 4] = rx1;
    Ctt[sk+0][sr]=rc0.x; Ctt[sk+1][sr]=rc0.y; Ctt[sk+2][sr]=rc0.z; Ctt[sk+3][sr]=rc0.w;
    Ctt[sk+4][sr]=rc1.x; Ctt[sk+5][sr]=rc1.y; Ctt[sk+6][sr]=rc1.z; Ctt[sk+7][sr]=rc1.w;
    Stt[sk+0][sr]=rs0.x; Stt[sk+1][sr]=rs0.y; Stt[sk+2][sr]=rs0.z; Stt[sk+3][sr]=rs0.w;
    Stt[sk+4][sr]=rs1.x; Stt[sk+5][sr]=rs1.y; Stt[sk+6][sr]=rs1.z; Stt[sk+7][sr]=rs1.w;
    __syncthreads();
    if (jt < 13) {
      const int j = (jt + 1) * 16;
      rx0 = *(const float4*)(xbase + (size_t)j * N224);
      rx1 = *(const float4*)(xbase + (size_t)j * N224 + 4);
      rc0 = *(const float4*)(cbase + j);
      rc1 = *(const float4*)(cbase + j + 4);
      rs0 = *(const float4*)(sbase + j);
      rs1 = *(const float4*)(sbase + j + 4);
    }
#pragma unroll
    for (int jj = 0; jj < 16; ++jj) {
      const float4 cv4 = *(const float4*)&Ctt[jj][4*ty];
      const float4 sv4 = *(const float4*)&Stt[jj][4*ty];
      const float4 xv4 = *(const float4*)&Xt[jj][4*tx];
      const float cva[4] = {cv4.x, cv4.y, cv4.z, cv4.w};
      const float sva[4] = {sv4.x, sv4.y, sv4.z, sv4.w};
      const float xva[4] = {xv4.x, xv4.y, xv4.z, xv4.w};
#pragma unroll
      for (int a = 0; a < 4; ++a)
#pragma unroll
        for (int d = 0; d < 4; ++d) {
          aC[a][d] = fmaf(cva[a], xva[d], aC[a][d]);
          aS[a][d] = fmaf(sva[a], xva[d], aS[a][d]);
        }
    }
  }
  const size_t b113 = (size_t)p * ROWS113;
#pragma unroll
  for (int a = 0; a < 4; ++a) {
    const int i = i0 + 4*ty + a;
    if (i <= 112) {
      const size_t off = b113 + (size_t)i * N224 + k0 + 4*tx;
      *(float4*)&Cx[off] = make_float4(aC[a][0], aC[a][1], aC[a][2], aC[a][3]);
      *(float4*)&Sx[off] = make_float4(aS[a][0], aS[a][1], aS[a][2], aS[a][3]);
    }
  }
}

// --------- DFT stage 2 (half rows, mirror writes): log|X| + fftshift --------
__global__ __launch_bounds__(64) void dft2(
    const float* __restrict__ Cx, const float* __restrict__ Sx,
    const float* __restrict__ Cm, const float* __restrict__ Sm,
    float* __restrict__ spec)
{
  const int p = blockIdx.z;
  const int i0 = blockIdx.y * 32;
  const int k0 = blockIdx.x * 32;
  const int tid = threadIdx.x;
  const int tx = tid & 7, ty = tid >> 3;
  const size_t b113 = (size_t)p * ROWS113;
  __shared__ float CxT[16][36], SxT[16][36], Ct[16][36], St[16][36];
  float p1[4][4], p2[4][4], p3[4][4], p4[4][4];
#pragma unroll
  for (int a = 0; a < 4; ++a)
#pragma unroll
    for (int d = 0; d < 4; ++d) { p1[a][d]=0.f; p2[a][d]=0.f; p3[a][d]=0.f; p4[a][d]=0.f; }

  const int sr = tid >> 1;
  const int sk = (tid & 1) * 8;
  const int ri = (i0 + sr > 112) ? 112 : i0 + sr;
  const int xj = tid >> 2;
  const int xk = (tid & 3) * 8;

  const float* cxb = Cx + b113 + (size_t)ri * N224 + sk;
  const float* sxb = Sx + b113 + (size_t)ri * N224 + sk;
  const float* ccb = Cm + (size_t)xj * N224 + k0 + xk;
  const float* ssb = Sm + (size_t)xj * N224 + k0 + xk;

  float4 ra0 = *(const float4*)(cxb);
  float4 ra1 = *(const float4*)(cxb + 4);
  float4 rb0 = *(const float4*)(sxb);
  float4 rb1 = *(const float4*)(sxb + 4);
  float4 rc0 = *(const float4*)(ccb);
  float4 rc1 = *(const float4*)(ccb + 4);
  float4 rd0 = *(const float4*)(ssb);
  float4 rd1 = *(const float4*)(ssb + 4);

  for (int jt = 0; jt < 14; ++jt) {
    __syncthreads();
    *(float4*)&Ct[xj][xk]     = rc0;  *(float4*)&Ct[xj][xk + 4] = rc1;
    *(float4*)&St[xj][xk]     = rd0;  *(float4*)&St[xj][xk + 4] = rd1;
    CxT[sk+0][sr]=ra0.x; CxT[sk+1][sr]=ra0.y; CxT[sk+2][sr]=ra0.z; CxT[sk+3][sr]=ra0.w;
    CxT[sk+4][sr]=ra1.x; CxT[sk+5][sr]=ra1.y; CxT[sk+6][sr]=ra1.z; CxT[sk+7][sr]=ra1.w;
    SxT[sk+0][sr]=rb0.x; SxT[sk+1][sr]=rb0.y; SxT[sk+2][sr]=rb0.z; SxT[sk+3][sr]=rb0.w;
    SxT[sk+4][sr]=rb1.x; SxT[sk+5][sr]=rb1.y; SxT[sk+6][sr]=rb1.z; SxT[sk+7][sr]=rb1.w;
    __syncthreads();
    if (jt < 13) {
      const int j = (jt + 1) * 16;
      ra0 = *(const float4*)(cxb + j);
      ra1 = *(const float4*)(cxb + j + 4);
      rb0 = *(const float4*)(sxb + j);
      rb1 = *(const float4*)(sxb + j + 4);
      rc0 = *(const float4*)(ccb + (size_t)j * N224);
      rc1 = *(const float4*)(ccb + (size_t)j * N224 + 4);
      rd0 = *(const float4*)(ssb + (size_t)j * N224);
      rd1 = *(const float4*)(ssb + (size_t)j * N224 + 4);
    }
#pragma unroll
    for (int jj = 0; jj < 16; ++jj) {
      const float4 cx4 = *(const float4*)&CxT[jj][4*ty];
      const float4 sx4 = *(const float4*)&SxT[jj][4*ty];
      const float4 cc4 = *(const float4*)&Ct[jj][4*tx];
      const float4 ss4 = *(const float4*)&St[jj][4*tx];
      const float cxa[4] = {cx4.x, cx4.y, cx4.z, cx4.w};
      const float sxa[4] = {sx4.x, sx4.y, sx4.z, sx4.w};
      const float cca[4] = {cc4.x, cc4.y, cc4.z, cc4.w};
      const float ssa[4] = {ss4.x, ss4.y, ss4.z, ss4.w};
#pragma unroll
      for (int a = 0; a < 4; ++a)
#pragma unroll
        for (int d = 0; d < 4; ++d) {
          p1[a][d] = fmaf(cxa[a], cca[d], p1[a][d]);
          p2[a][d] = fmaf(sxa[a], ssa[d], p2[a][d]);
          p3[a][d] = fmaf(cxa[a], ssa[d], p3[a][d]);
          p4[a][d] = fmaf(sxa[a], cca[d], p4[a][d]);
        }
    }
  }
  const size_t sb = (size_t)p * PIX;
  const int kk0 = k0 + 4*tx;
  const int ok0 = (kk0 < 112) ? kk0 + 112 : kk0 - 112;
#pragma unroll
  for (int a = 0; a < 4; ++a) {
    const int i = i0 + 4*ty + a;
    if (i > 112) continue;
    float sp1[4], sp2[4];
#pragma unroll
    for (int d = 0; d < 4; ++d) {
      const float re = p1[a][d] - p2[a][d];
      const float im = p3[a][d] + p4[a][d];
      sp1[d] = logf(sqrtf(fmaf(re, re, fmaf(im, im, 1e-8f))) + 1e-8f);
      const float re2 = p1[a][d] + p2[a][d];
      const float im2 = p3[a][d] - p4[a][d];
      sp2[d] = logf(sqrtf(fmaf(re2, re2, fmaf(im2, im2, 1e-8f))) + 1e-8f);
    }
    const int oi = (i < 112) ? i + 112 : i - 112;
    *(float4*)&spec[sb + (size_t)oi * N224 + ok0] =
        make_float4(sp1[0], sp1[1], sp1[2], sp1[3]);
    if (i >= 1 && i <= 111)
      *(float4*)&spec[sb + (size_t)(112 - i) * N224 + ok0] =
          make_float4(sp2[0], sp2[1], sp2[2], sp2[3]);
  }
}

// -------- conv1 (3->16)+BN+ReLU+pool: co-major lanes, b128 broadcasts -------
// grid (56,16): band = 2 pooled rows (4 conv rows, 6 input rows).
// wave w: pr=w>>1 (pooled row), xh=w&1 (conv x-half of 112).
// lane: co = lane&15, xsub = lane>>4 (28 conv px each).
__global__ __launch_bounds__(256) void conv1(
    const float* __restrict__ spec, const float* __restrict__ wt1,
    const float* __restrict__ su1, float* __restrict__ out)
{
  const int band = blockIdx.x, b = blockIdx.y;
  const int tid = threadIdx.x;
  const int w = tid >> 6, lane = tid & 63;
  const int co = lane & 15, xsub = lane >> 4;
  __shared__ float in_t[3][6][232];
  for (int i = tid; i < 3*6*232; i += 256) {
    const int c = i % 232, j = (i / 232) % 6, cc = i / 1392;
    const int y = band*4 - 1 + j, gx = c - 1;
    float v = 0.f;
    if (c < 226 && y >= 0 && y < 224 && gx >= 0 && gx < 224)
      v = spec[((size_t)b*3 + cc) * PIX + (size_t)y * N224 + gx];
    in_t[cc][j][c] = v;
  }
  __syncthreads();
  const int pr = w >> 1, xh = w & 1;
  const int X0 = xh*112 + xsub*28;     // multiple of 4
  const int jb = 2*pr;                 // input rows jb..jb+3
  float acc[2][28];
#pragma unroll
  for (int r = 0; r < 2; ++r)
#pragma unroll
    for (int px = 0; px < 28; ++px) acc[r][px] = 0.f;
#pragma unroll
  for (int cc = 0; cc < 3; ++cc) {
    float wr[9];
#pragma unroll
    for (int k = 0; k < 9; ++k) wr[k] = wt1[(cc*9 + k)*16 + co];
#pragma unroll
    for (int rr = 0; rr < 4; ++rr) {
      float xr[32];
      const float4* rp = (const float4*)&in_t[cc][jb+rr][X0];
#pragma unroll
      for (int t = 0; t < 8; ++t) {
        const float4 v = rp[t];
        xr[4*t]=v.x; xr[4*t+1]=v.y; xr[4*t+2]=v.z; xr[4*t+3]=v.w;
      }
#pragma unroll
      for (int cr = 0; cr < 2; ++cr) {
        const int ky = rr - cr;
        if (ky < 0 || ky > 2) continue;
#pragma unroll
        for (int px = 0; px < 28; ++px) {
          acc[cr][px] = fmaf(xr[px  ], wr[ky*3  ], acc[cr][px]);
          acc[cr][px] = fmaf(xr[px+1], wr[ky*3+1], acc[cr][px]);
          acc[cr][px] = fmaf(xr[px+2], wr[ky*3+2], acc[cr][px]);
        }
      }
    }
  }
  const float s = su1[co], u = su1[16+co];
  const int py = band*2 + pr, pxb = X0 >> 1;
#pragma unroll
  for (int p = 0; p < 14; ++p) {
    const float v0 = acc[0][2*p]*s + u,   v1 = acc[0][2*p+1]*s + u;
    const float v2 = acc[1][2*p]*s + u,   v3 = acc[1][2*p+1]*s + u;
    out[(((size_t)b*16 + co)*112 + py)*112 + pxb + p] =
        fmaxf(fmaxf(fmaxf(v0, v1), fmaxf(v2, v3)), 0.f);
  }
}

// -------- conv2 (16->32)+BN+ReLU+pool: co-major lanes, b128 broadcasts ------
// grid (28,16): band = 2 pooled rows (4 conv rows, 6 input rows of 112).
// wave w: pr=w>>1, xh=w&1 (conv x-half of 56). lane: co=lane&31, xsub=lane>>5.
__global__ __launch_bounds__(256) void conv2(
    const float* __restrict__ h1, const float* __restrict__ wt2,
    const float* __restrict__ su2, float* __restrict__ out)
{
  const int band = blockIdx.x, b = blockIdx.y;
  const int tid = threadIdx.x;
  const int w = tid >> 6, lane = tid & 63;
  const int co = lane & 31, xsub = lane >> 5;
  __shared__ float in_t[16][6][120];
  for (int i = tid; i < 16*6*120; i += 256) {
    const int c = i % 120, j = (i / 120) % 6, cc = i / 720;
    const int y = band*4 - 1 + j, gx = c - 1;
    float v = 0.f;
    if (c < 114 && y >= 0 && y < 112 && gx >= 0 && gx < 112)
      v = h1[(((size_t)b*16 + cc)*112 + y)*112 + gx];
    in_t[cc][j][c] = v;
  }
  __syncthreads();
  const int pr = w >> 1, xh = w & 1;
  const int X0 = xh*56 + xsub*28;      // 0,28,56,84 — multiple of 4
  const int jb = 2*pr;
  float acc[2][28];
#pragma unroll
  for (int r = 0; r < 2; ++r)
#pragma unroll
    for (int px = 0; px < 28; ++px) acc[r][px] = 0.f;
  for (int cc = 0; cc < 16; ++cc) {
    float wr[9];
#pragma unroll
    for (int k = 0; k < 9; ++k) wr[k] = wt2[(cc*9 + k)*32 + co];
#pragma unroll
    for (int rr = 0; rr < 4; ++rr) {
      float xr[32];
      const float4* rp = (const float4*)&in_t[cc][jb+rr][X0];
#pragma unroll
      for (int t = 0; t < 8; ++t) {
        const float4 v = rp[t];
        xr[4*t]=v.x; xr[4*t+1]=v.y; xr[4*t+2]=v.z; xr[4*t+3]=v.w;
      }
#pragma unroll
      for (int cr = 0; cr < 2; ++cr) {
        const int ky = rr - cr;
        if (ky < 0 || ky > 2) continue;
#pragma unroll
        for (int px = 0; px < 28; ++px) {
          acc[cr][px] = fmaf(xr[px  ], wr[ky*3  ], acc[cr][px]);
          acc[cr][px] = fmaf(xr[px+1], wr[ky*3+1], acc[cr][px]);
          acc[cr][px] = fmaf(xr[px+2], wr[ky*3+2], acc[cr][px]);
        }
      }
    }
  }
  const float s = su2[co], u = su2[32+co];
  const int py = band*2 + pr, pxb = X0 >> 1;
#pragma unroll
  for (int p = 0; p < 14; ++p) {
    const float v0 = acc[0][2*p]*s + u,   v1 = acc[0][2*p+1]*s + u;
    const float v2 = acc[1][2*p]*s + u,   v3 = acc[1][2*p+1]*s + u;
    out[(((size_t)b*32 + co)*56 + py)*56 + pxb + p] =
        fmaxf(fmaxf(fmaxf(v0, v1), fmaxf(v2, v3)), 0.f);
  }
}

// -------- conv3 (32->64)+BN+ReLU+partial mean: co-major, pure broadcast -----
// grid (28,16): band = 2 output rows (4 input rows of 56).
// wave w: rb=w>>1 (output row), xh=w&1 (x-half of 28). lane = co (64).
__global__ __launch_bounds__(256) void conv3(
    const float* __restrict__ h2, const float* __restrict__ wt3,
    const float* __restrict__ su3, float* __restrict__ part)
{
  const int band = blockIdx.x, b = blockIdx.y;
  const int tid = threadIdx.x;
  const int w = tid >> 6, co = tid & 63;
  __shared__ float in_t[32][4][60];
  for (int i = tid; i < 32*4*60; i += 256) {
    const int c = i % 60, j = (i / 60) % 4, cc = i / 240;
    const int y = band*2 - 1 + j, gx = c - 1;
    float v = 0.f;
    if (c < 58 && y >= 0 && y < 56 && gx >= 0 && gx < 56)
      v = h2[(((size_t)b*32 + cc)*56 + y)*56 + gx];
    in_t[cc][j][c] = v;
  }
  __syncthreads();
  const int rb = w >> 1, xh = w & 1;
  const int X0 = xh * 28;
  float acc[28];
#pragma unroll
  for (int px = 0; px < 28; ++px) acc[px] = 0.f;
  for (int cc = 0; cc < 32; ++cc) {
    float wr[9];
#pragma unroll
    for (int k = 0; k < 9; ++k) wr[k] = wt3[(cc*9 + k)*64 + co];
#pragma unroll
    for (int rr = 0; rr < 3; ++rr) {
      float xr[32];
      const float4* rp = (const float4*)&in_t[cc][rb+rr][X0];
#pragma unroll
      for (int t = 0; t < 8; ++t) {
        const float4 v = rp[t];
        xr[4*t]=v.x; xr[4*t+1]=v.y; xr[4*t+2]=v.z; xr[4*t+3]=v.w;
      }
#pragma unroll
      for (int px = 0; px < 28; ++px) {
        acc[px] = fmaf(xr[px  ], wr[rr*3  ], acc[px]);
        acc[px] = fmaf(xr[px+1], wr[rr*3+1], acc[px]);
        acc[px] = fmaf(xr[px+2], wr[rr*3+2], acc[px]);
      }
    }
  }
  const float s = su3[co], u = su3[64+co];
  float sum = 0.f;
#pragma unroll
  for (int px = 0; px < 28; ++px)
    sum += fmaxf(acc[px]*s + u, 0.f);
  part[((size_t)b*64 + co)*112 + band*4 + w] = sum;
}

// ------------- global mean (112 partials) + FC + ReLU -----------------------
__global__ __launch_bounds__(128) void mean_fc(
    const float* __restrict__ part, const float* __restrict__ fw,
    const float* __restrict__ fb, float* __restrict__ out)
{
  const int b = blockIdx.x;
  const int tid = threadIdx.x;
  __shared__ float h3s[64];
  if (tid < 64) {
    float s = 0.f;
    const float* pp = part + ((size_t)b*64 + tid)*112;
#pragma unroll
    for (int i = 0; i < 112; ++i) s += pp[i];
    h3s[tid] = s * (1.0f / 3136.0f);
  }
  __syncthreads();
  float acc = fb[tid];
#pragma unroll
  for (int c = 0; c < 64; ++c)
    acc = fmaf(h3s[c], fw[tid*64 + c], acc);
  out[b*128 + tid] = fmaxf(acc, 0.f);
}

extern "C" void kernel_launch(void* const* d_in, const int* in_sizes, int n_in,
                              void* d_out, int out_size, void* d_ws, size_t ws_size,
                              hipStream_t stream) {
  const float* seq  = (const float*)d_in[0];
  const float* dcos = (const float*)d_in[1];
  const float* dsin = (const float*)d_in[2];
  const float* c1w  = (const float*)d_in[3];
  const float* c1b  = (const float*)d_in[4];
  const float* b1g  = (const float*)d_in[5];
  const float* b1b  = (const float*)d_in[6];
  const float* b1m  = (const float*)d_in[7];
  const float* b1v  = (const float*)d_in[8];
  const float* c2w  = (const float*)d_in[9];
  const float* c2b  = (const float*)d_in[10];
  const float* b2g  = (const float*)d_in[11];
  const float* b2b  = (const float*)d_in[12];
  const float* b2m  = (const float*)d_in[13];
  const float* b2v  = (const float*)d_in[14];
  const float* c3w  = (const float*)d_in[15];
  const float* c3b  = (const float*)d_in[16];
  const float* b3g  = (const float*)d_in[17];
  const float* b3b  = (const float*)d_in[18];
  const float* b3m  = (const float*)d_in[19];
  const float* b3v  = (const float*)d_in[20];
  const float* fw   = (const float*)d_in[21];
  const float* fb   = (const float*)d_in[22];
  float* out = (float*)d_out;

  float* ws   = (float*)d_ws;
  float* Cx   = ws;                   // 1,214,976 (113 rows x 224, 48 imgs)
  float* Sx   = ws + OFF_SX;          // 1,214,976
  float* spec = ws + OFF_SPEC;        // 2,408,448
  float* h1   = ws;                   // 3,211,264 (reuses dead Cx/Sx)
  float* h2   = ws + OFF_SPEC;        // 1,605,632 (reuses dead spec)
  float* wt3  = ws + OFF_WT;
  float* wt2  = ws + OFF_WT2;
  float* wt1  = ws + OFF_WT1;
  float* su3  = ws + OFF_SU3;
  float* su2  = ws + OFF_SU2;
  float* su1  = ws + OFF_SU1;
  float* part = ws + OFF_PART;        // 114,688

  prep<<<24, 256, 0, stream>>>(c1w, c2w, c3w, c1b, c2b, c3b,
                               b1g, b1b, b1m, b1v, b2g, b2b, b2m, b2v,
                               b3g, b3b, b3m, b3v, wt3, wt2, wt1, su3, su2, su1);
  dft1<<<dim3(7, 4, 48), 64, 0, stream>>>(seq, dcos, dsin, Cx, Sx);
  dft2<<<dim3(7, 4, 48), 64, 0, stream>>>(Cx, Sx, dcos, dsin, spec);
  conv1<<<dim3(56, 16), 256, 0, stream>>>(spec, wt1, su1, h1);
  conv2<<<dim3(28, 16), 256, 0, stream>>>(h1, wt2, su2, h2);
  conv3<<<dim3(28, 16), 256, 0, stream>>>(h2, wt3, su3, part);
  mean_fc<<<16, 128, 0, stream>>>(part, fw, fb, out);
}

// Round 6
// 191.331 us; speedup vs baseline: 1.0356x; 1.0356x over previous
//
#include <hip/hip_runtime.h>
#include <math.h>
#include <stddef.h>

#define N224 224
#define PIX 50176      // 224*224
#define ROWS113 25312  // 113*224, Cx/Sx rows per image

// ---- ws float offsets ----
#define OFF_SX    1214976
#define OFF_SPEC  4816896
#define OFF_WT    3211264              // right after h1 (16*16*112*112)
#define OFF_WT2   (OFF_WT + 18432)
#define OFF_WT1   (OFF_WT + 23040)
#define OFF_SU3   (OFF_WT + 23472)    // [64 s][64 u]
#define OFF_SU2   (OFF_WT + 23600)    // [32 s][32 u]
#define OFF_SU1   (OFF_WT + 23664)    // [16 s][16 u]
#define OFF_PART  (OFF_WT + 32768)    // 16*64*112 = 114688 floats

// ---------------- prep: weight transpose + BN fold --------------------------
__global__ __launch_bounds__(256) void prep(
    const float* __restrict__ c1w, const float* __restrict__ c2w,
    const float* __restrict__ c3w, const float* __restrict__ c1b,
    const float* __restrict__ c2b, const float* __restrict__ c3b,
    const float* __restrict__ g1, const float* __restrict__ be1,
    const float* __restrict__ m1, const float* __restrict__ v1,
    const float* __restrict__ g2, const float* __restrict__ be2,
    const float* __restrict__ m2, const float* __restrict__ v2,
    const float* __restrict__ g3, const float* __restrict__ be3,
    const float* __restrict__ m3, const float* __restrict__ v3,
    float* __restrict__ wt3, float* __restrict__ wt2, float* __restrict__ wt1,
    float* __restrict__ su3, float* __restrict__ su2, float* __restrict__ su1)
{
  const int idx = blockIdx.x * 256 + threadIdx.x;
  const int stride = gridDim.x * 256;
  for (int i = idx; i < 18432; i += stride) {          // wT3[(cc*9+k)*64+co]
    const int co = i & 63, k = (i >> 6) % 9, cc = i / 576;
    wt3[i] = c3w[co*288 + cc*9 + k];
  }
  for (int i = idx; i < 4608; i += stride) {           // wT2[(cc*9+k)*32+co]
    const int co = i & 31, k = (i >> 5) % 9, cc = i / 288;
    wt2[i] = c2w[co*144 + cc*9 + k];
  }
  for (int i = idx; i < 432; i += stride) {            // wT1[(cc*9+k)*16+co]
    const int co = i & 15, k = (i >> 4) % 9, cc = i / 144;
    wt1[i] = c1w[co*27 + cc*9 + k];
  }
  if (idx < 64) {
    const float s = g3[idx] * rsqrtf(v3[idx] + 1e-5f);
    su3[idx] = s; su3[64+idx] = (c3b[idx] - m3[idx]) * s + be3[idx];
  } else if (idx < 96) {
    const int c = idx - 64;
    const float s = g2[c] * rsqrtf(v2[c] + 1e-5f);
    su2[c] = s; su2[32+c] = (c2b[c] - m2[c]) * s + be2[c];
  } else if (idx < 112) {
    const int c = idx - 96;
    const float s = g1[c] * rsqrtf(v1[c] + 1e-5f);
    su1[c] = s; su1[16+c] = (c1b[c] - m1[c]) * s + be1[c];
  }
}

// ---------------- DFT stage 1 (half rows): Cx = C @ x, Sx = S @ x -----------
// Rows i = 0..112 only. grid (7 k-tiles, 4 i-tiles, 48), block 256 = 16x16,
// 32x32 tile, 2x2 micro-tile. High occupancy (4 waves/block, 5376 waves).
__global__ __launch_bounds__(256) void dft1(
    const float* __restrict__ seq, const float* __restrict__ Cm,
    const float* __restrict__ Sm, float* __restrict__ Cx, float* __restrict__ Sx)
{
  const int p = blockIdx.z;
  const int b = p / 3, ch = p % 3;
  const float* __restrict__ x = seq + ((((size_t)b * 8 + 4) * 3 + ch) * PIX);
  const int i0 = blockIdx.y * 32;      // 0,32,64,96 (rows >112 masked on store)
  const int k0 = blockIdx.x * 32;
  const int tid = threadIdx.x;
  const int tx = tid & 15, ty = tid >> 4;
  __shared__ float Ctt[16][36], Stt[16][36], Xt[16][36];
  float aC[2][2] = {{0,0},{0,0}}, aS[2][2] = {{0,0},{0,0}};

  // staging roles
  const int sidx = tid & 127;
  const int srow = sidx >> 2;          // 0..31 (C/S row)
  const int skq  = (sidx & 3) * 4;     // 0,4,8,12 (k quad)
  const bool isC = tid < 128;
  const float* __restrict__ csb = (isC ? Cm : Sm) + (size_t)(i0 + srow) * N224 + skq;
  const int xjr = tid >> 4;            // 0..15 (j row)
  const int xc  = (tid & 15) * 2;      // 0..30 (col pair)
  const float* __restrict__ xb = x + (size_t)xjr * N224 + k0 + xc;

  for (int jt = 0; jt < 14; ++jt) {
    const int j = jt * 16;
    __syncthreads();
    {
      const float4 v = *(const float4*)(csb + j);
      float (*dst)[36] = isC ? Ctt : Stt;
      dst[skq+0][srow] = v.x; dst[skq+1][srow] = v.y;
      dst[skq+2][srow] = v.z; dst[skq+3][srow] = v.w;
      *(float2*)&Xt[xjr][xc] = *(const float2*)(xb + (size_t)j * N224);
    }
    __syncthreads();
#pragma unroll
    for (int jj = 0; jj < 16; ++jj) {
      const float2 cv = *(const float2*)&Ctt[jj][2*ty];
      const float2 sv = *(const float2*)&Stt[jj][2*ty];
      const float2 xv = *(const float2*)&Xt[jj][2*tx];
      aC[0][0] = fmaf(cv.x, xv.x, aC[0][0]); aC[0][1] = fmaf(cv.x, xv.y, aC[0][1]);
      aC[1][0] = fmaf(cv.y, xv.x, aC[1][0]); aC[1][1] = fmaf(cv.y, xv.y, aC[1][1]);
      aS[0][0] = fmaf(sv.x, xv.x, aS[0][0]); aS[0][1] = fmaf(sv.x, xv.y, aS[0][1]);
      aS[1][0] = fmaf(sv.y, xv.x, aS[1][0]); aS[1][1] = fmaf(sv.y, xv.y, aS[1][1]);
    }
  }
  const size_t b113 = (size_t)p * ROWS113;
#pragma unroll
  for (int a = 0; a < 2; ++a) {
    const int i = i0 + 2*ty + a;
    if (i <= 112) {
      const size_t off = b113 + (size_t)i * N224 + k0 + 2*tx;
      *(float2*)&Cx[off] = make_float2(aC[a][0], aC[a][1]);
      *(float2*)&Sx[off] = make_float2(aS[a][0], aS[a][1]);
    }
  }
}

// --------- DFT stage 2 (QUARTER grid): log|X| + fftshift, 4-way mirror ------
// P1=Cx@C, P2=Sx@S, P3=Cx@S, P4=Sx@C for i,k in 0..112.
//  (i,k) & (224-i,224-k):  |(P1-P2, P3+P4)|
//  (224-i,k) & (i,224-k):  |(P1+P2, P3-P4)|
// grid (4 k-tiles, 4 i-tiles, 48), block 256 = 16x16, 32x32 tile, 2x2 micro.
__global__ __launch_bounds__(256) void dft2(
    const float* __restrict__ Cx, const float* __restrict__ Sx,
    const float* __restrict__ Cm, const float* __restrict__ Sm,
    float* __restrict__ spec)
{
  const int p = blockIdx.z;
  const int i0 = blockIdx.y * 32;      // 0,32,64,96 (masked > 112)
  const int k0 = blockIdx.x * 32;      // 0,32,64,96 (masked > 112)
  const int tid = threadIdx.x;
  const int tx = tid & 15, ty = tid >> 4;
  const size_t b113 = (size_t)p * ROWS113;
  __shared__ float CxT[16][36], SxT[16][36], Ct[16][36], St[16][36];
  float p1[2][2] = {{0,0},{0,0}}, p2[2][2] = {{0,0},{0,0}};
  float p3[2][2] = {{0,0},{0,0}}, p4[2][2] = {{0,0},{0,0}};

  // staging roles
  const int sidx = tid & 127;
  const int srow = sidx >> 2;                      // 0..31
  const int skq  = (sidx & 3) * 4;                 // 0,4,8,12
  const bool isCx = tid < 128;
  const int ri = (i0 + srow > 112) ? 112 : i0 + srow;   // clamp (masked later)
  const float* __restrict__ ab = (isCx ? Cx : Sx) + b113 + (size_t)ri * N224 + skq;
  const int jr = tid >> 4;                         // 0..15
  const int cc2 = (tid & 15) * 2;                  // 0..30
  const float* __restrict__ cb = Cm + (size_t)jr * N224 + k0 + cc2;
  const float* __restrict__ sb2 = Sm + (size_t)jr * N224 + k0 + cc2;

  for (int jt = 0; jt < 14; ++jt) {
    const int j = jt * 16;
    __syncthreads();
    {
      const float4 v = *(const float4*)(ab + j);
      float (*dst)[36] = isCx ? CxT : SxT;
      dst[skq+0][srow] = v.x; dst[skq+1][srow] = v.y;
      dst[skq+2][srow] = v.z; dst[skq+3][srow] = v.w;
      *(float2*)&Ct[jr][cc2] = *(const float2*)(cb + (size_t)j * N224);
      *(float2*)&St[jr][cc2] = *(const float2*)(sb2 + (size_t)j * N224);
    }
    __syncthreads();
#pragma unroll
    for (int jj = 0; jj < 16; ++jj) {
      const float2 cxv = *(const float2*)&CxT[jj][2*ty];
      const float2 sxv = *(const float2*)&SxT[jj][2*ty];
      const float2 ccv = *(const float2*)&Ct[jj][2*tx];
      const float2 ssv = *(const float2*)&St[jj][2*tx];
      const float cxa[2] = {cxv.x, cxv.y};
      const float sxa[2] = {sxv.x, sxv.y};
      const float cca[2] = {ccv.x, ccv.y};
      const float ssa[2] = {ssv.x, ssv.y};
#pragma unroll
      for (int a = 0; a < 2; ++a)
#pragma unroll
        for (int d = 0; d < 2; ++d) {
          p1[a][d] = fmaf(cxa[a], cca[d], p1[a][d]);
          p2[a][d] = fmaf(sxa[a], ssa[d], p2[a][d]);
          p3[a][d] = fmaf(cxa[a], ssa[d], p3[a][d]);
          p4[a][d] = fmaf(sxa[a], cca[d], p4[a][d]);
        }
    }
  }
  const size_t sb = (size_t)p * PIX;
#pragma unroll
  for (int a = 0; a < 2; ++a) {
    const int i = i0 + 2*ty + a;
    if (i > 112) continue;
    const int shi  = (i < 112) ? i + 112 : i - 112;  // sh(i)
    const int shmi = 112 - i;                        // sh(224-i), valid 1..111
    const bool irm = (i >= 1) && (i <= 111);
#pragma unroll
    for (int d = 0; d < 2; ++d) {
      const int k = k0 + 2*tx + d;
      if (k > 112) continue;
      const float r1 = p1[a][d] - p2[a][d];
      const float i1 = p3[a][d] + p4[a][d];
      const float sp1v = logf(sqrtf(fmaf(r1, r1, fmaf(i1, i1, 1e-8f))) + 1e-8f);
      const float r2v = p1[a][d] + p2[a][d];
      const float i2v = p3[a][d] - p4[a][d];
      const float sp2v = logf(sqrtf(fmaf(r2v, r2v, fmaf(i2v, i2v, 1e-8f))) + 1e-8f);
      const int shk  = (k < 112) ? k + 112 : k - 112;
      const int shmk = 112 - k;
      const bool krm = (k >= 1) && (k <= 111);
      spec[sb + (size_t)shi*N224 + shk] = sp1v;
      if (irm)        spec[sb + (size_t)shmi*N224 + shk ] = sp2v;
      if (krm)        spec[sb + (size_t)shi *N224 + shmk] = sp2v;
      if (irm && krm) spec[sb + (size_t)shmi*N224 + shmk] = sp1v;
    }
  }
}

// -------- conv1 (3->16)+BN+ReLU+pool: co-major lanes, b128 broadcasts -------
__global__ __launch_bounds__(256) void conv1(
    const float* __restrict__ spec, const float* __restrict__ wt1,
    const float* __restrict__ su1, float* __restrict__ out)
{
  const int band = blockIdx.x, b = blockIdx.y;
  const int tid = threadIdx.x;
  const int w = tid >> 6, lane = tid & 63;
  const int co = lane & 15, xsub = lane >> 4;
  __shared__ float in_t[3][6][232];
  for (int i = tid; i < 3*6*232; i += 256) {
    const int c = i % 232, j = (i / 232) % 6, cc = i / 1392;
    const int y = band*4 - 1 + j, gx = c - 1;
    float v = 0.f;
    if (c < 226 && y >= 0 && y < 224 && gx >= 0 && gx < 224)
      v = spec[((size_t)b*3 + cc) * PIX + (size_t)y * N224 + gx];
    in_t[cc][j][c] = v;
  }
  __syncthreads();
  const int pr = w >> 1, xh = w & 1;
  const int X0 = xh*112 + xsub*28;
  const int jb = 2*pr;
  float acc[2][28];
#pragma unroll
  for (int r = 0; r < 2; ++r)
#pragma unroll
    for (int px = 0; px < 28; ++px) acc[r][px] = 0.f;
#pragma unroll
  for (int cc = 0; cc < 3; ++cc) {
    float wr[9];
#pragma unroll
    for (int k = 0; k < 9; ++k) wr[k] = wt1[(cc*9 + k)*16 + co];
#pragma unroll
    for (int rr = 0; rr < 4; ++rr) {
      float xr[32];
      const float4* rp = (const float4*)&in_t[cc][jb+rr][X0];
#pragma unroll
      for (int t = 0; t < 8; ++t) {
        const float4 v = rp[t];
        xr[4*t]=v.x; xr[4*t+1]=v.y; xr[4*t+2]=v.z; xr[4*t+3]=v.w;
      }
#pragma unroll
      for (int cr = 0; cr < 2; ++cr) {
        const int ky = rr - cr;
        if (ky < 0 || ky > 2) continue;
#pragma unroll
        for (int px = 0; px < 28; ++px) {
          acc[cr][px] = fmaf(xr[px  ], wr[ky*3  ], acc[cr][px]);
          acc[cr][px] = fmaf(xr[px+1], wr[ky*3+1], acc[cr][px]);
          acc[cr][px] = fmaf(xr[px+2], wr[ky*3+2], acc[cr][px]);
        }
      }
    }
  }
  const float s = su1[co], u = su1[16+co];
  const int py = band*2 + pr, pxb = X0 >> 1;
#pragma unroll
  for (int p = 0; p < 14; ++p) {
    const float v0 = acc[0][2*p]*s + u,   v1 = acc[0][2*p+1]*s + u;
    const float v2 = acc[1][2*p]*s + u,   v3 = acc[1][2*p+1]*s + u;
    out[(((size_t)b*16 + co)*112 + py)*112 + pxb + p] =
        fmaxf(fmaxf(fmaxf(v0, v1), fmaxf(v2, v3)), 0.f);
  }
}

// -------- conv2 (16->32)+BN+ReLU+pool: co-major lanes, b128 broadcasts ------
__global__ __launch_bounds__(256) void conv2(
    const float* __restrict__ h1, const float* __restrict__ wt2,
    const float* __restrict__ su2, float* __restrict__ out)
{
  const int band = blockIdx.x, b = blockIdx.y;
  const int tid = threadIdx.x;
  const int w = tid >> 6, lane = tid & 63;
  const int co = lane & 31, xsub = lane >> 5;
  __shared__ float in_t[16][6][120];
  for (int i = tid; i < 16*6*120; i += 256) {
    const int c = i % 120, j = (i / 120) % 6, cc = i / 720;
    const int y = band*4 - 1 + j, gx = c - 1;
    float v = 0.f;
    if (c < 114 && y >= 0 && y < 112 && gx >= 0 && gx < 112)
      v = h1[(((size_t)b*16 + cc)*112 + y)*112 + gx];
    in_t[cc][j][c] = v;
  }
  __syncthreads();
  const int pr = w >> 1, xh = w & 1;
  const int X0 = xh*56 + xsub*28;
  const int jb = 2*pr;
  float acc[2][28];
#pragma unroll
  for (int r = 0; r < 2; ++r)
#pragma unroll
    for (int px = 0; px < 28; ++px) acc[r][px] = 0.f;
  for (int cc = 0; cc < 16; ++cc) {
    float wr[9];
#pragma unroll
    for (int k = 0; k < 9; ++k) wr[k] = wt2[(cc*9 + k)*32 + co];
#pragma unroll
    for (int rr = 0; rr < 4; ++rr) {
      float xr[32];
      const float4* rp = (const float4*)&in_t[cc][jb+rr][X0];
#pragma unroll
      for (int t = 0; t < 8; ++t) {
        const float4 v = rp[t];
        xr[4*t]=v.x; xr[4*t+1]=v.y; xr[4*t+2]=v.z; xr[4*t+3]=v.w;
      }
#pragma unroll
      for (int cr = 0; cr < 2; ++cr) {
        const int ky = rr - cr;
        if (ky < 0 || ky > 2) continue;
#pragma unroll
        for (int px = 0; px < 28; ++px) {
          acc[cr][px] = fmaf(xr[px  ], wr[ky*3  ], acc[cr][px]);
          acc[cr][px] = fmaf(xr[px+1], wr[ky*3+1], acc[cr][px]);
          acc[cr][px] = fmaf(xr[px+2], wr[ky*3+2], acc[cr][px]);
        }
      }
    }
  }
  const float s = su2[co], u = su2[32+co];
  const int py = band*2 + pr, pxb = X0 >> 1;
#pragma unroll
  for (int p = 0; p < 14; ++p) {
    const float v0 = acc[0][2*p]*s + u,   v1 = acc[0][2*p+1]*s + u;
    const float v2 = acc[1][2*p]*s + u,   v3 = acc[1][2*p+1]*s + u;
    out[(((size_t)b*32 + co)*56 + py)*56 + pxb + p] =
        fmaxf(fmaxf(fmaxf(v0, v1), fmaxf(v2, v3)), 0.f);
  }
}

// -------- conv3 (32->64)+BN+ReLU+partial mean: co-major, pure broadcast -----
__global__ __launch_bounds__(256) void conv3(
    const float* __restrict__ h2, const float* __restrict__ wt3,
    const float* __restrict__ su3, float* __restrict__ part)
{
  const int band = blockIdx.x, b = blockIdx.y;
  const int tid = threadIdx.x;
  const int w = tid >> 6, co = tid & 63;
  __shared__ float in_t[32][4][60];
  for (int i = tid; i < 32*4*60; i += 256) {
    const int c = i % 60, j = (i / 60) % 4, cc = i / 240;
    const int y = band*2 - 1 + j, gx = c - 1;
    float v = 0.f;
    if (c < 58 && y >= 0 && y < 56 && gx >= 0 && gx < 56)
      v = h2[(((size_t)b*32 + cc)*56 + y)*56 + gx];
    in_t[cc][j][c] = v;
  }
  __syncthreads();
  const int rb = w >> 1, xh = w & 1;
  const int X0 = xh * 28;
  float acc[28];
#pragma unroll
  for (int px = 0; px < 28; ++px) acc[px] = 0.f;
  for (int cc = 0; cc < 32; ++cc) {
    float wr[9];
#pragma unroll
    for (int k = 0; k < 9; ++k) wr[k] = wt3[(cc*9 + k)*64 + co];
#pragma unroll
    for (int rr = 0; rr < 3; ++rr) {
      float xr[32];
      const float4* rp = (const float4*)&in_t[cc][rb+rr][X0];
#pragma unroll
      for (int t = 0; t < 8; ++t) {
        const float4 v = rp[t];
        xr[4*t]=v.x; xr[4*t+1]=v.y; xr[4*t+2]=v.z; xr[4*t+3]=v.w;
      }
#pragma unroll
      for (int px = 0; px < 28; ++px) {
        acc[px] = fmaf(xr[px  ], wr[rr*3  ], acc[px]);
        acc[px] = fmaf(xr[px+1], wr[rr*3+1], acc[px]);
        acc[px] = fmaf(xr[px+2], wr[rr*3+2], acc[px]);
      }
    }
  }
  const float s = su3[co], u = su3[64+co];
  float sum = 0.f;
#pragma unroll
  for (int px = 0; px < 28; ++px)
    sum += fmaxf(acc[px]*s + u, 0.f);
  part[((size_t)b*64 + co)*112 + band*4 + w] = sum;
}

// ------------- global mean (112 partials) + FC + ReLU -----------------------
__global__ __launch_bounds__(128) void mean_fc(
    const float* __restrict__ part, const float* __restrict__ fw,
    const float* __restrict__ fb, float* __restrict__ out)
{
  const int b = blockIdx.x;
  const int tid = threadIdx.x;
  __shared__ float h3s[64];
  if (tid < 64) {
    float s = 0.f;
    const float* pp = part + ((size_t)b*64 + tid)*112;
#pragma unroll
    for (int i = 0; i < 112; ++i) s += pp[i];
    h3s[tid] = s * (1.0f / 3136.0f);
  }
  __syncthreads();
  float acc = fb[tid];
#pragma unroll
  for (int c = 0; c < 64; ++c)
    acc = fmaf(h3s[c], fw[tid*64 + c], acc);
  out[b*128 + tid] = fmaxf(acc, 0.f);
}

extern "C" void kernel_launch(void* const* d_in, const int* in_sizes, int n_in,
                              void* d_out, int out_size, void* d_ws, size_t ws_size,
                              hipStream_t stream) {
  const float* seq  = (const float*)d_in[0];
  const float* dcos = (const float*)d_in[1];
  const float* dsin = (const float*)d_in[2];
  const float* c1w  = (const float*)d_in[3];
  const float* c1b  = (const float*)d_in[4];
  const float* b1g  = (const float*)d_in[5];
  const float* b1b  = (const float*)d_in[6];
  const float* b1m  = (const float*)d_in[7];
  const float* b1v  = (const float*)d_in[8];
  const float* c2w  = (const float*)d_in[9];
  const float* c2b  = (const float*)d_in[10];
  const float* b2g  = (const float*)d_in[11];
  const float* b2b  = (const float*)d_in[12];
  const float* b2m  = (const float*)d_in[13];
  const float* b2v  = (const float*)d_in[14];
  const float* c3w  = (const float*)d_in[15];
  const float* c3b  = (const float*)d_in[16];
  const float* b3g  = (const float*)d_in[17];
  const float* b3b  = (const float*)d_in[18];
  const float* b3m  = (const float*)d_in[19];
  const float* b3v  = (const float*)d_in[20];
  const float* fw   = (const float*)d_in[21];
  const float* fb   = (const float*)d_in[22];
  float* out = (float*)d_out;

  float* ws   = (float*)d_ws;
  float* Cx   = ws;                   // 1,214,976 (113 rows x 224, 48 imgs)
  float* Sx   = ws + OFF_SX;          // 1,214,976
  float* spec = ws + OFF_SPEC;        // 2,408,448
  float* h1   = ws;                   // 3,211,264 (reuses dead Cx/Sx)
  float* h2   = ws + OFF_SPEC;        // 1,605,632 (reuses dead spec)
  float* wt3  = ws + OFF_WT;
  float* wt2  = ws + OFF_WT2;
  float* wt1  = ws + OFF_WT1;
  float* su3  = ws + OFF_SU3;
  float* su2  = ws + OFF_SU2;
  float* su1  = ws + OFF_SU1;
  float* part = ws + OFF_PART;        // 114,688

  prep<<<24, 256, 0, stream>>>(c1w, c2w, c3w, c1b, c2b, c3b,
                               b1g, b1b, b1m, b1v, b2g, b2b, b2m, b2v,
                               b3g, b3b, b3m, b3v, wt3, wt2, wt1, su3, su2, su1);
  dft1<<<dim3(7, 4, 48), 256, 0, stream>>>(seq, dcos, dsin, Cx, Sx);
  dft2<<<dim3(4, 4, 48), 256, 0, stream>>>(Cx, Sx, dcos, dsin, spec);
  conv1<<<dim3(56, 16), 256, 0, stream>>>(spec, wt1, su1, h1);
  conv2<<<dim3(28, 16), 256, 0, stream>>>(h1, wt2, su2, h2);
  conv3<<<dim3(28, 16), 256, 0, stream>>>(h2, wt3, su3, part);
  mean_fc<<<16, 128, 0, stream>>>(part, fw, fb, out);
}

// Round 8
// 164.029 us; speedup vs baseline: 1.2079x; 1.1664x over previous
//
#include <hip/hip_runtime.h>
#include <math.h>
#include <stddef.h>

#define N224 224
#define PIX 50176      // 224*224
#define ROWS113 25312  // 113*224, Cx/Sx rows per image

// ---- ws float offsets ----
#define OFF_SX    1214976
#define OFF_SPEC  4816896
#define OFF_WT    3211264              // right after h1 (16*16*112*112)
#define OFF_WT2   (OFF_WT + 18432)
#define OFF_WT1   (OFF_WT + 23040)
#define OFF_SU3   (OFF_WT + 23472)    // [64 s][64 u]
#define OFF_SU2   (OFF_WT + 23600)    // [32 s][32 u]
#define OFF_SU1   (OFF_WT + 23664)    // [16 s][16 u]
#define OFF_PART  (OFF_WT + 32768)    // 16*64*56 = 57344 floats

// ---------------- prep: weight transpose + BN fold --------------------------
__global__ __launch_bounds__(256) void prep(
    const float* __restrict__ c1w, const float* __restrict__ c2w,
    const float* __restrict__ c3w, const float* __restrict__ c1b,
    const float* __restrict__ c2b, const float* __restrict__ c3b,
    const float* __restrict__ g1, const float* __restrict__ be1,
    const float* __restrict__ m1, const float* __restrict__ v1,
    const float* __restrict__ g2, const float* __restrict__ be2,
    const float* __restrict__ m2, const float* __restrict__ v2,
    const float* __restrict__ g3, const float* __restrict__ be3,
    const float* __restrict__ m3, const float* __restrict__ v3,
    float* __restrict__ wt3, float* __restrict__ wt2, float* __restrict__ wt1,
    float* __restrict__ su3, float* __restrict__ su2, float* __restrict__ su1)
{
  const int idx = blockIdx.x * 256 + threadIdx.x;
  const int stride = gridDim.x * 256;
  for (int i = idx; i < 18432; i += stride) {          // wT3[(cc*9+k)*64+co]
    const int co = i & 63, k = (i >> 6) % 9, cc = i / 576;
    wt3[i] = c3w[co*288 + cc*9 + k];
  }
  for (int i = idx; i < 4608; i += stride) {           // wT2[(cc*9+k)*32+co]
    const int co = i & 31, k = (i >> 5) % 9, cc = i / 288;
    wt2[i] = c2w[co*144 + cc*9 + k];
  }
  for (int i = idx; i < 432; i += stride) {            // wT1[(cc*9+k)*16+co]
    const int co = i & 15, k = (i >> 4) % 9, cc = i / 144;
    wt1[i] = c1w[co*27 + cc*9 + k];
  }
  if (idx < 64) {
    const float s = g3[idx] * rsqrtf(v3[idx] + 1e-5f);
    su3[idx] = s; su3[64+idx] = (c3b[idx] - m3[idx]) * s + be3[idx];
  } else if (idx < 96) {
    const int c = idx - 64;
    const float s = g2[c] * rsqrtf(v2[c] + 1e-5f);
    su2[c] = s; su2[32+c] = (c2b[c] - m2[c]) * s + be2[c];
  } else if (idx < 112) {
    const int c = idx - 96;
    const float s = g1[c] * rsqrtf(v1[c] + 1e-5f);
    su1[c] = s; su1[16+c] = (c1b[c] - m1[c]) * s + be1[c];
  }
}

// ---------------- DFT stage 1 (half rows): Cx = C @ x, Sx = S @ x -----------
__global__ __launch_bounds__(256) void dft1(
    const float* __restrict__ seq, const float* __restrict__ Cm,
    const float* __restrict__ Sm, float* __restrict__ Cx, float* __restrict__ Sx)
{
  const int p = blockIdx.z;
  const int b = p / 3, ch = p % 3;
  const float* __restrict__ x = seq + ((((size_t)b * 8 + 4) * 3 + ch) * PIX);
  const int i0 = blockIdx.y * 32;
  const int k0 = blockIdx.x * 32;
  const int tid = threadIdx.x;
  const int tx = tid & 15, ty = tid >> 4;
  __shared__ float Ctt[16][36], Stt[16][36], Xt[16][36];
  float aC[2][2] = {{0,0},{0,0}}, aS[2][2] = {{0,0},{0,0}};

  const int sidx = tid & 127;
  const int srow = sidx >> 2;
  const int skq  = (sidx & 3) * 4;
  const bool isC = tid < 128;
  const float* __restrict__ csb = (isC ? Cm : Sm) + (size_t)(i0 + srow) * N224 + skq;
  const int xjr = tid >> 4;
  const int xc  = (tid & 15) * 2;
  const float* __restrict__ xb = x + (size_t)xjr * N224 + k0 + xc;

  for (int jt = 0; jt < 14; ++jt) {
    const int j = jt * 16;
    __syncthreads();
    {
      const float4 v = *(const float4*)(csb + j);
      float (*dst)[36] = isC ? Ctt : Stt;
      dst[skq+0][srow] = v.x; dst[skq+1][srow] = v.y;
      dst[skq+2][srow] = v.z; dst[skq+3][srow] = v.w;
      *(float2*)&Xt[xjr][xc] = *(const float2*)(xb + (size_t)j * N224);
    }
    __syncthreads();
#pragma unroll
    for (int jj = 0; jj < 16; ++jj) {
      const float2 cv = *(const float2*)&Ctt[jj][2*ty];
      const float2 sv = *(const float2*)&Stt[jj][2*ty];
      const float2 xv = *(const float2*)&Xt[jj][2*tx];
      aC[0][0] = fmaf(cv.x, xv.x, aC[0][0]); aC[0][1] = fmaf(cv.x, xv.y, aC[0][1]);
      aC[1][0] = fmaf(cv.y, xv.x, aC[1][0]); aC[1][1] = fmaf(cv.y, xv.y, aC[1][1]);
      aS[0][0] = fmaf(sv.x, xv.x, aS[0][0]); aS[0][1] = fmaf(sv.x, xv.y, aS[0][1]);
      aS[1][0] = fmaf(sv.y, xv.x, aS[1][0]); aS[1][1] = fmaf(sv.y, xv.y, aS[1][1]);
    }
  }
  const size_t b113 = (size_t)p * ROWS113;
#pragma unroll
  for (int a = 0; a < 2; ++a) {
    const int i = i0 + 2*ty + a;
    if (i <= 112) {
      const size_t off = b113 + (size_t)i * N224 + k0 + 2*tx;
      *(float2*)&Cx[off] = make_float2(aC[a][0], aC[a][1]);
      *(float2*)&Sx[off] = make_float2(aS[a][0], aS[a][1]);
    }
  }
}

// --------- DFT stage 2 (QUARTER grid): log|X| + fftshift, 4-way mirror ------
__global__ __launch_bounds__(256) void dft2(
    const float* __restrict__ Cx, const float* __restrict__ Sx,
    const float* __restrict__ Cm, const float* __restrict__ Sm,
    float* __restrict__ spec)
{
  const int p = blockIdx.z;
  const int i0 = blockIdx.y * 32;
  const int k0 = blockIdx.x * 32;
  const int tid = threadIdx.x;
  const int tx = tid & 15, ty = tid >> 4;
  const size_t b113 = (size_t)p * ROWS113;
  __shared__ float CxT[16][36], SxT[16][36], Ct[16][36], St[16][36];
  float p1[2][2] = {{0,0},{0,0}}, p2[2][2] = {{0,0},{0,0}};
  float p3[2][2] = {{0,0},{0,0}}, p4[2][2] = {{0,0},{0,0}};

  const int sidx = tid & 127;
  const int srow = sidx >> 2;
  const int skq  = (sidx & 3) * 4;
  const bool isCx = tid < 128;
  const int ri = (i0 + srow > 112) ? 112 : i0 + srow;
  const float* __restrict__ ab = (isCx ? Cx : Sx) + b113 + (size_t)ri * N224 + skq;
  const int jr = tid >> 4;
  const int cc2 = (tid & 15) * 2;
  const float* __restrict__ cb = Cm + (size_t)jr * N224 + k0 + cc2;
  const float* __restrict__ sb2 = Sm + (size_t)jr * N224 + k0 + cc2;

  for (int jt = 0; jt < 14; ++jt) {
    const int j = jt * 16;
    __syncthreads();
    {
      const float4 v = *(const float4*)(ab + j);
      float (*dst)[36] = isCx ? CxT : SxT;
      dst[skq+0][srow] = v.x; dst[skq+1][srow] = v.y;
      dst[skq+2][srow] = v.z; dst[skq+3][srow] = v.w;
      *(float2*)&Ct[jr][cc2] = *(const float2*)(cb + (size_t)j * N224);
      *(float2*)&St[jr][cc2] = *(const float2*)(sb2 + (size_t)j * N224);
    }
    __syncthreads();
#pragma unroll
    for (int jj = 0; jj < 16; ++jj) {
      const float2 cxv = *(const float2*)&CxT[jj][2*ty];
      const float2 sxv = *(const float2*)&SxT[jj][2*ty];
      const float2 ccv = *(const float2*)&Ct[jj][2*tx];
      const float2 ssv = *(const float2*)&St[jj][2*tx];
      const float cxa[2] = {cxv.x, cxv.y};
      const float sxa[2] = {sxv.x, sxv.y};
      const float cca[2] = {ccv.x, ccv.y};
      const float ssa[2] = {ssv.x, ssv.y};
#pragma unroll
      for (int a = 0; a < 2; ++a)
#pragma unroll
        for (int d = 0; d < 2; ++d) {
          p1[a][d] = fmaf(cxa[a], cca[d], p1[a][d]);
          p2[a][d] = fmaf(sxa[a], ssa[d], p2[a][d]);
          p3[a][d] = fmaf(cxa[a], ssa[d], p3[a][d]);
          p4[a][d] = fmaf(sxa[a], cca[d], p4[a][d]);
        }
    }
  }
  const size_t sb = (size_t)p * PIX;
#pragma unroll
  for (int a = 0; a < 2; ++a) {
    const int i = i0 + 2*ty + a;
    if (i > 112) continue;
    const int shi  = (i < 112) ? i + 112 : i - 112;
    const int shmi = 112 - i;
    const bool irm = (i >= 1) && (i <= 111);
#pragma unroll
    for (int d = 0; d < 2; ++d) {
      const int k = k0 + 2*tx + d;
      if (k > 112) continue;
      const float r1 = p1[a][d] - p2[a][d];
      const float i1 = p3[a][d] + p4[a][d];
      const float sp1v = logf(sqrtf(fmaf(r1, r1, fmaf(i1, i1, 1e-8f))) + 1e-8f);
      const float r2v = p1[a][d] + p2[a][d];
      const float i2v = p3[a][d] - p4[a][d];
      const float sp2v = logf(sqrtf(fmaf(r2v, r2v, fmaf(i2v, i2v, 1e-8f))) + 1e-8f);
      const int shk  = (k < 112) ? k + 112 : k - 112;
      const int shmk = 112 - k;
      const bool krm = (k >= 1) && (k <= 111);
      spec[sb + (size_t)shi*N224 + shk] = sp1v;
      if (irm)        spec[sb + (size_t)shmi*N224 + shk ] = sp2v;
      if (krm)        spec[sb + (size_t)shi *N224 + shmk] = sp2v;
      if (irm && krm) spec[sb + (size_t)shmi*N224 + shmk] = sp1v;
    }
  }
}

// -------- conv1 (3->16)+BN+ReLU+pool: lane-cr split, shfl pool --------------
// grid (112 pooled-row, 16 b). lane: co=&15, cr=(>>4)&1, xs=>>5. wave: xh,xq.
__global__ __launch_bounds__(256) void conv1(
    const float* __restrict__ spec, const float* __restrict__ wt1,
    const float* __restrict__ su1, float* __restrict__ out)
{
  const int band = blockIdx.x, b = blockIdx.y;
  const int tid = threadIdx.x;
  const int lane = tid & 63, w = tid >> 6;
  const int co = lane & 15, cr = (lane >> 4) & 1, xs = lane >> 5;
  const int xh = w >> 1, xq = w & 1;
  __shared__ float in_t[3][4][232];
  for (int i = tid; i < 3*4*232; i += 256) {
    const int c = i % 232, r = (i / 232) % 4, cc = i / 928;
    const int y = band*2 - 1 + r, gx = c - 1;
    float v = 0.f;
    if (c < 226 && y >= 0 && y < 224 && gx >= 0 && gx < 224)
      v = spec[((size_t)b*3 + cc) * PIX + (size_t)y * N224 + gx];
    in_t[cc][r][c] = v;
  }
  __syncthreads();
  const int X0 = xh*112 + xq*56 + xs*28;   // 0..196 step 28, 16B-aligned
  float acc[28];
#pragma unroll
  for (int px = 0; px < 28; ++px) acc[px] = 0.f;
#pragma unroll
  for (int cc = 0; cc < 3; ++cc) {
    float wr[9];
#pragma unroll
    for (int k = 0; k < 9; ++k) wr[k] = wt1[(cc*9 + k)*16 + co];
#pragma unroll
    for (int ky = 0; ky < 3; ++ky) {
      float xr[32];
      const float4* rp = (const float4*)&in_t[cc][cr + ky][X0];
#pragma unroll
      for (int t = 0; t < 8; ++t) {
        const float4 v = rp[t];
        xr[4*t]=v.x; xr[4*t+1]=v.y; xr[4*t+2]=v.z; xr[4*t+3]=v.w;
      }
#pragma unroll
      for (int px = 0; px < 28; ++px) {
        acc[px] = fmaf(xr[px  ], wr[ky*3  ], acc[px]);
        acc[px] = fmaf(xr[px+1], wr[ky*3+1], acc[px]);
        acc[px] = fmaf(xr[px+2], wr[ky*3+2], acc[px]);
      }
    }
  }
  const float s = su1[co], u = su1[16+co];
  float m[14];
#pragma unroll
  for (int p = 0; p < 14; ++p)
    m[p] = fmaxf(acc[2*p]*s + u, acc[2*p+1]*s + u);
#pragma unroll
  for (int p = 0; p < 14; ++p) {
    const float pm = __shfl_xor(m[p], 16);
    m[p] = fmaxf(fmaxf(m[p], pm), 0.f);
  }
  if (cr == 0) {
    const int pxb = X0 >> 1;
    float* op = &out[(((size_t)b*16 + co)*112 + band)*112 + pxb];
#pragma unroll
    for (int p = 0; p < 14; ++p) op[p] = m[p];
  }
}

// -------- conv2 (16->32)+BN+ReLU+pool: lane-cr split, shfl pool -------------
// grid (2 xh, 56 pooled-row, 16 b). lane: co=&31, cr=>>5. wave: 14-px slice.
__global__ __launch_bounds__(256) void conv2(
    const float* __restrict__ h1, const float* __restrict__ wt2,
    const float* __restrict__ su2, float* __restrict__ out)
{
  const int xh = blockIdx.x, band = blockIdx.y, b = blockIdx.z;
  const int tid = threadIdx.x;
  const int lane = tid & 63, w = tid >> 6;
  const int co = lane & 31, cr = lane >> 5;
  __shared__ float in_t[16][4][64];
  for (int i = tid; i < 16*4*58; i += 256) {
    const int c = i % 58, r = (i / 58) % 4, cc = i / 232;
    const int y = band*2 - 1 + r, gx = xh*56 - 1 + c;
    float v = 0.f;
    if (y >= 0 && y < 112 && gx >= 0 && gx < 112)
      v = h1[(((size_t)b*16 + cc)*112 + y)*112 + gx];
    in_t[cc][r][c] = v;
  }
  __syncthreads();
  const int X0 = w * 14;                   // 0,14,28,42 — 8B-aligned
  float acc[14];
#pragma unroll
  for (int px = 0; px < 14; ++px) acc[px] = 0.f;
  for (int cc = 0; cc < 16; ++cc) {
    float wr[9];
#pragma unroll
    for (int k = 0; k < 9; ++k) wr[k] = wt2[(cc*9 + k)*32 + co];
#pragma unroll
    for (int ky = 0; ky < 3; ++ky) {
      float xr[16];
      const float2* rp = (const float2*)&in_t[cc][cr + ky][X0];
#pragma unroll
      for (int t = 0; t < 8; ++t) {
        const float2 v = rp[t];
        xr[2*t] = v.x; xr[2*t+1] = v.y;
      }
#pragma unroll
      for (int px = 0; px < 14; ++px) {
        acc[px] = fmaf(xr[px  ], wr[ky*3  ], acc[px]);
        acc[px] = fmaf(xr[px+1], wr[ky*3+1], acc[px]);
        acc[px] = fmaf(xr[px+2], wr[ky*3+2], acc[px]);
      }
    }
  }
  const float s = su2[co], u = su2[32+co];
  float m[7];
#pragma unroll
  for (int p = 0; p < 7; ++p)
    m[p] = fmaxf(acc[2*p]*s + u, acc[2*p+1]*s + u);
#pragma unroll
  for (int p = 0; p < 7; ++p) {
    const float pm = __shfl_xor(m[p], 32);
    m[p] = fmaxf(fmaxf(m[p], pm), 0.f);
  }
  if (cr == 0) {
    float* op = &out[(((size_t)b*32 + co)*56 + band)*56 + xh*28 + w*7];
#pragma unroll
    for (int p = 0; p < 7; ++p) op[p] = m[p];
  }
}

// -------- conv3 (32->64)+BN+ReLU+partial mean: 1 row/block ------------------
// grid (56 row, 16 b). 256 thr = 64 co x 4 x-slices of 14.
__global__ __launch_bounds__(256) void conv3(
    const float* __restrict__ h2, const float* __restrict__ wt3,
    const float* __restrict__ su3, float* __restrict__ part)
{
  const int band = blockIdx.x, b = blockIdx.y;
  const int tid = threadIdx.x;
  const int co = tid & 63, w = tid >> 6;
  __shared__ float in_t[32][3][64];
  __shared__ float red[4][64];
  for (int i = tid; i < 32*3*58; i += 256) {
    const int c = i % 58, r = (i / 58) % 3, cc = i / 174;
    const int y = band - 1 + r, gx = c - 1;
    float v = 0.f;
    if (y >= 0 && y < 56 && gx >= 0 && gx < 56)
      v = h2[(((size_t)b*32 + cc)*56 + y)*56 + gx];
    in_t[cc][r][c] = v;
  }
  __syncthreads();
  const int X0 = w * 14;
  float acc[14];
#pragma unroll
  for (int px = 0; px < 14; ++px) acc[px] = 0.f;
  for (int cc = 0; cc < 32; ++cc) {
    float wr[9];
#pragma unroll
    for (int k = 0; k < 9; ++k) wr[k] = wt3[(cc*9 + k)*64 + co];
#pragma unroll
    for (int rr = 0; rr < 3; ++rr) {
      float xr[16];
      const float2* rp = (const float2*)&in_t[cc][rr][X0];
#pragma unroll
      for (int t = 0; t < 8; ++t) {
        const float2 v = rp[t];
        xr[2*t] = v.x; xr[2*t+1] = v.y;
      }
#pragma unroll
      for (int px = 0; px < 14; ++px) {
        acc[px] = fmaf(xr[px  ], wr[rr*3  ], acc[px]);
        acc[px] = fmaf(xr[px+1], wr[rr*3+1], acc[px]);
        acc[px] = fmaf(xr[px+2], wr[rr*3+2], acc[px]);
      }
    }
  }
  const float s = su3[co], u = su3[64+co];
  float sum = 0.f;
#pragma unroll
  for (int px = 0; px < 14; ++px)
    sum += fmaxf(acc[px]*s + u, 0.f);
  red[w][co] = sum;
  __syncthreads();
  if (tid < 64)
    part[((size_t)b*64 + co)*56 + band] =
        red[0][co] + red[1][co] + red[2][co] + red[3][co];
}

// ------------- global mean (56 partials) + FC + ReLU ------------------------
__global__ __launch_bounds__(128) void mean_fc(
    const float* __restrict__ part, const float* __restrict__ fw,
    const float* __restrict__ fb, float* __restrict__ out)
{
  const int b = blockIdx.x;
  const int tid = threadIdx.x;
  __shared__ float h3s[64];
  if (tid < 64) {
    float s = 0.f;
    const float* pp = part + ((size_t)b*64 + tid)*56;
#pragma unroll
    for (int i = 0; i < 56; ++i) s += pp[i];
    h3s[tid] = s * (1.0f / 3136.0f);
  }
  __syncthreads();
  float acc = fb[tid];
#pragma unroll
  for (int c = 0; c < 64; ++c)
    acc = fmaf(h3s[c], fw[tid*64 + c], acc);
  out[b*128 + tid] = fmaxf(acc, 0.f);
}

extern "C" void kernel_launch(void* const* d_in, const int* in_sizes, int n_in,
                              void* d_out, int out_size, void* d_ws, size_t ws_size,
                              hipStream_t stream) {
  const float* seq  = (const float*)d_in[0];
  const float* dcos = (const float*)d_in[1];
  const float* dsin = (const float*)d_in[2];
  const float* c1w  = (const float*)d_in[3];
  const float* c1b  = (const float*)d_in[4];
  const float* b1g  = (const float*)d_in[5];
  const float* b1b  = (const float*)d_in[6];
  const float* b1m  = (const float*)d_in[7];
  const float* b1v  = (const float*)d_in[8];
  const float* c2w  = (const float*)d_in[9];
  const float* c2b  = (const float*)d_in[10];
  const float* b2g  = (const float*)d_in[11];
  const float* b2b  = (const float*)d_in[12];
  const float* b2m  = (const float*)d_in[13];
  const float* b2v  = (const float*)d_in[14];
  const float* c3w  = (const float*)d_in[15];
  const float* c3b  = (const float*)d_in[16];
  const float* b3g  = (const float*)d_in[17];
  const float* b3b  = (const float*)d_in[18];
  const float* b3m  = (const float*)d_in[19];
  const float* b3v  = (const float*)d_in[20];
  const float* fw   = (const float*)d_in[21];
  const float* fb   = (const float*)d_in[22];
  float* out = (float*)d_out;

  float* ws   = (float*)d_ws;
  float* Cx   = ws;                   // 1,214,976 (113 rows x 224, 48 imgs)
  float* Sx   = ws + OFF_SX;          // 1,214,976
  float* spec = ws + OFF_SPEC;        // 2,408,448
  float* h1   = ws;                   // 3,211,264 (reuses dead Cx/Sx)
  float* h2   = ws + OFF_SPEC;        // 1,605,632 (reuses dead spec)
  float* wt3  = ws + OFF_WT;
  float* wt2  = ws + OFF_WT2;
  float* wt1  = ws + OFF_WT1;
  float* su3  = ws + OFF_SU3;
  float* su2  = ws + OFF_SU2;
  float* su1  = ws + OFF_SU1;
  float* part = ws + OFF_PART;        // 57,344

  prep<<<24, 256, 0, stream>>>(c1w, c2w, c3w, c1b, c2b, c3b,
                               b1g, b1b, b1m, b1v, b2g, b2b, b2m, b2v,
                               b3g, b3b, b3m, b3v, wt3, wt2, wt1, su3, su2, su1);
  dft1<<<dim3(7, 4, 48), 256, 0, stream>>>(seq, dcos, dsin, Cx, Sx);
  dft2<<<dim3(4, 4, 48), 256, 0, stream>>>(Cx, Sx, dcos, dsin, spec);
  conv1<<<dim3(112, 16), 256, 0, stream>>>(spec, wt1, su1, h1);
  conv2<<<dim3(2, 56, 16), 256, 0, stream>>>(h1, wt2, su2, h2);
  conv3<<<dim3(56, 16), 256, 0, stream>>>(h2, wt3, su3, part);
  mean_fc<<<16, 128, 0, stream>>>(part, fw, fb, out);
}

// Round 9
// 163.315 us; speedup vs baseline: 1.2132x; 1.0044x over previous
//
#include <hip/hip_runtime.h>
#include <math.h>
#include <stddef.h>

#define N224 224
#define PIX 50176      // 224*224
#define ROWS113 25312  // 113*224, Cx/Sx rows per image

// ---- ws float offsets ----
#define OFF_SX    1214976
#define OFF_SPEC  4816896
#define OFF_WT    3211264              // right after h1 (16*16*112*112)
#define OFF_WT2   (OFF_WT + 24576)    // wt3v = 32*64*12
#define OFF_WT1   (OFF_WT + 30720)    // wt2v = 16*32*12
#define OFF_SU3   (OFF_WT + 31296)    // wt1v = 3*16*12
#define OFF_SU2   (OFF_WT + 31424)    // su3 = 128
#define OFF_SU1   (OFF_WT + 31488)    // su2 = 64
#define OFF_PART  (OFF_WT + 32768)    // 16*64*56 = 57344 floats

// ---------------- prep: weight transpose (vectorized layout) + BN fold ------
// wtNv[cc][co][12]: k=0..8 real, 9..11 zero pad -> per-thread 16B-aligned rows
__global__ __launch_bounds__(256) void prep(
    const float* __restrict__ c1w, const float* __restrict__ c2w,
    const float* __restrict__ c3w, const float* __restrict__ c1b,
    const float* __restrict__ c2b, const float* __restrict__ c3b,
    const float* __restrict__ g1, const float* __restrict__ be1,
    const float* __restrict__ m1, const float* __restrict__ v1,
    const float* __restrict__ g2, const float* __restrict__ be2,
    const float* __restrict__ m2, const float* __restrict__ v2,
    const float* __restrict__ g3, const float* __restrict__ be3,
    const float* __restrict__ m3, const float* __restrict__ v3,
    float* __restrict__ wt3, float* __restrict__ wt2, float* __restrict__ wt1,
    float* __restrict__ su3, float* __restrict__ su2, float* __restrict__ su1)
{
  const int idx = blockIdx.x * 256 + threadIdx.x;
  const int stride = gridDim.x * 256;
  for (int i = idx; i < 32*64*12; i += stride) {       // wt3v[cc*768+co*12+k]
    const int cc = i / 768, r = i % 768, co = r / 12, k = r % 12;
    wt3[i] = (k < 9) ? c3w[co*288 + cc*9 + k] : 0.f;
  }
  for (int i = idx; i < 16*32*12; i += stride) {       // wt2v[cc*384+co*12+k]
    const int cc = i / 384, r = i % 384, co = r / 12, k = r % 12;
    wt2[i] = (k < 9) ? c2w[co*144 + cc*9 + k] : 0.f;
  }
  for (int i = idx; i < 3*16*12; i += stride) {        // wt1v[cc*192+co*12+k]
    const int cc = i / 192, r = i % 192, co = r / 12, k = r % 12;
    wt1[i] = (k < 9) ? c1w[co*27 + cc*9 + k] : 0.f;
  }
  if (idx < 64) {
    const float s = g3[idx] * rsqrtf(v3[idx] + 1e-5f);
    su3[idx] = s; su3[64+idx] = (c3b[idx] - m3[idx]) * s + be3[idx];
  } else if (idx < 96) {
    const int c = idx - 64;
    const float s = g2[c] * rsqrtf(v2[c] + 1e-5f);
    su2[c] = s; su2[32+c] = (c2b[c] - m2[c]) * s + be2[c];
  } else if (idx < 112) {
    const int c = idx - 96;
    const float s = g1[c] * rsqrtf(v1[c] + 1e-5f);
    su1[c] = s; su1[16+c] = (c1b[c] - m1[c]) * s + be1[c];
  }
}

// ---------------- DFT stage 1 (half rows): Cx = C @ x, Sx = S @ x -----------
__global__ __launch_bounds__(256) void dft1(
    const float* __restrict__ seq, const float* __restrict__ Cm,
    const float* __restrict__ Sm, float* __restrict__ Cx, float* __restrict__ Sx)
{
  const int p = blockIdx.z;
  const int b = p / 3, ch = p % 3;
  const float* __restrict__ x = seq + ((((size_t)b * 8 + 4) * 3 + ch) * PIX);
  const int i0 = blockIdx.y * 32;
  const int k0 = blockIdx.x * 32;
  const int tid = threadIdx.x;
  const int tx = tid & 15, ty = tid >> 4;
  __shared__ float Ctt[16][36], Stt[16][36], Xt[16][36];
  float aC[2][2] = {{0,0},{0,0}}, aS[2][2] = {{0,0},{0,0}};

  const int sidx = tid & 127;
  const int srow = sidx >> 2;
  const int skq  = (sidx & 3) * 4;
  const bool isC = tid < 128;
  const float* __restrict__ csb = (isC ? Cm : Sm) + (size_t)(i0 + srow) * N224 + skq;
  const int xjr = tid >> 4;
  const int xc  = (tid & 15) * 2;
  const float* __restrict__ xb = x + (size_t)xjr * N224 + k0 + xc;

  for (int jt = 0; jt < 14; ++jt) {
    const int j = jt * 16;
    __syncthreads();
    {
      const float4 v = *(const float4*)(csb + j);
      float (*dst)[36] = isC ? Ctt : Stt;
      dst[skq+0][srow] = v.x; dst[skq+1][srow] = v.y;
      dst[skq+2][srow] = v.z; dst[skq+3][srow] = v.w;
      *(float2*)&Xt[xjr][xc] = *(const float2*)(xb + (size_t)j * N224);
    }
    __syncthreads();
#pragma unroll
    for (int jj = 0; jj < 16; ++jj) {
      const float2 cv = *(const float2*)&Ctt[jj][2*ty];
      const float2 sv = *(const float2*)&Stt[jj][2*ty];
      const float2 xv = *(const float2*)&Xt[jj][2*tx];
      aC[0][0] = fmaf(cv.x, xv.x, aC[0][0]); aC[0][1] = fmaf(cv.x, xv.y, aC[0][1]);
      aC[1][0] = fmaf(cv.y, xv.x, aC[1][0]); aC[1][1] = fmaf(cv.y, xv.y, aC[1][1]);
      aS[0][0] = fmaf(sv.x, xv.x, aS[0][0]); aS[0][1] = fmaf(sv.x, xv.y, aS[0][1]);
      aS[1][0] = fmaf(sv.y, xv.x, aS[1][0]); aS[1][1] = fmaf(sv.y, xv.y, aS[1][1]);
    }
  }
  const size_t b113 = (size_t)p * ROWS113;
#pragma unroll
  for (int a = 0; a < 2; ++a) {
    const int i = i0 + 2*ty + a;
    if (i <= 112) {
      const size_t off = b113 + (size_t)i * N224 + k0 + 2*tx;
      *(float2*)&Cx[off] = make_float2(aC[a][0], aC[a][1]);
      *(float2*)&Sx[off] = make_float2(aS[a][0], aS[a][1]);
    }
  }
}

// --------- DFT stage 2 (QUARTER grid): log|X| + fftshift, 4-way mirror ------
__global__ __launch_bounds__(256) void dft2(
    const float* __restrict__ Cx, const float* __restrict__ Sx,
    const float* __restrict__ Cm, const float* __restrict__ Sm,
    float* __restrict__ spec)
{
  const int p = blockIdx.z;
  const int i0 = blockIdx.y * 32;
  const int k0 = blockIdx.x * 32;
  const int tid = threadIdx.x;
  const int tx = tid & 15, ty = tid >> 4;
  const size_t b113 = (size_t)p * ROWS113;
  __shared__ float CxT[16][36], SxT[16][36], Ct[16][36], St[16][36];
  float p1[2][2] = {{0,0},{0,0}}, p2[2][2] = {{0,0},{0,0}};
  float p3[2][2] = {{0,0},{0,0}}, p4[2][2] = {{0,0},{0,0}};

  const int sidx = tid & 127;
  const int srow = sidx >> 2;
  const int skq  = (sidx & 3) * 4;
  const bool isCx = tid < 128;
  const int ri = (i0 + srow > 112) ? 112 : i0 + srow;
  const float* __restrict__ ab = (isCx ? Cx : Sx) + b113 + (size_t)ri * N224 + skq;
  const int jr = tid >> 4;
  const int cc2 = (tid & 15) * 2;
  const float* __restrict__ cb = Cm + (size_t)jr * N224 + k0 + cc2;
  const float* __restrict__ sb2 = Sm + (size_t)jr * N224 + k0 + cc2;

  for (int jt = 0; jt < 14; ++jt) {
    const int j = jt * 16;
    __syncthreads();
    {
      const float4 v = *(const float4*)(ab + j);
      float (*dst)[36] = isCx ? CxT : SxT;
      dst[skq+0][srow] = v.x; dst[skq+1][srow] = v.y;
      dst[skq+2][srow] = v.z; dst[skq+3][srow] = v.w;
      *(float2*)&Ct[jr][cc2] = *(const float2*)(cb + (size_t)j * N224);
      *(float2*)&St[jr][cc2] = *(const float2*)(sb2 + (size_t)j * N224);
    }
    __syncthreads();
#pragma unroll
    for (int jj = 0; jj < 16; ++jj) {
      const float2 cxv = *(const float2*)&CxT[jj][2*ty];
      const float2 sxv = *(const float2*)&SxT[jj][2*ty];
      const float2 ccv = *(const float2*)&Ct[jj][2*tx];
      const float2 ssv = *(const float2*)&St[jj][2*tx];
      const float cxa[2] = {cxv.x, cxv.y};
      const float sxa[2] = {sxv.x, sxv.y};
      const float cca[2] = {ccv.x, ccv.y};
      const float ssa[2] = {ssv.x, ssv.y};
#pragma unroll
      for (int a = 0; a < 2; ++a)
#pragma unroll
        for (int d = 0; d < 2; ++d) {
          p1[a][d] = fmaf(cxa[a], cca[d], p1[a][d]);
          p2[a][d] = fmaf(sxa[a], ssa[d], p2[a][d]);
          p3[a][d] = fmaf(cxa[a], ssa[d], p3[a][d]);
          p4[a][d] = fmaf(sxa[a], cca[d], p4[a][d]);
        }
    }
  }
  const size_t sb = (size_t)p * PIX;
#pragma unroll
  for (int a = 0; a < 2; ++a) {
    const int i = i0 + 2*ty + a;
    if (i > 112) continue;
    const int shi  = (i < 112) ? i + 112 : i - 112;
    const int shmi = 112 - i;
    const bool irm = (i >= 1) && (i <= 111);
#pragma unroll
    for (int d = 0; d < 2; ++d) {
      const int k = k0 + 2*tx + d;
      if (k > 112) continue;
      const float r1 = p1[a][d] - p2[a][d];
      const float i1 = p3[a][d] + p4[a][d];
      const float sp1v = logf(sqrtf(fmaf(r1, r1, fmaf(i1, i1, 1e-8f))) + 1e-8f);
      const float r2v = p1[a][d] + p2[a][d];
      const float i2v = p3[a][d] - p4[a][d];
      const float sp2v = logf(sqrtf(fmaf(r2v, r2v, fmaf(i2v, i2v, 1e-8f))) + 1e-8f);
      const int shk  = (k < 112) ? k + 112 : k - 112;
      const int shmk = 112 - k;
      const bool krm = (k >= 1) && (k <= 111);
      spec[sb + (size_t)shi*N224 + shk] = sp1v;
      if (irm)        spec[sb + (size_t)shmi*N224 + shk ] = sp2v;
      if (krm)        spec[sb + (size_t)shi *N224 + shmk] = sp2v;
      if (irm && krm) spec[sb + (size_t)shmi*N224 + shmk] = sp1v;
    }
  }
}

// -------- conv1 (3->16)+BN+ReLU+pool: lane-cr split, shfl pool --------------
// grid (112 pooled-row, 16 b). lane: co=&15, cr=(>>4)&1, xs=>>5. wave: xh,xq.
__global__ __launch_bounds__(256) void conv1(
    const float* __restrict__ spec, const float* __restrict__ wt1,
    const float* __restrict__ su1, float* __restrict__ out)
{
  const int band = blockIdx.x, b = blockIdx.y;
  const int tid = threadIdx.x;
  const int lane = tid & 63, w = tid >> 6;
  const int co = lane & 15, cr = (lane >> 4) & 1, xs = lane >> 5;
  const int xh = w >> 1, xq = w & 1;
  __shared__ float in_t[3][4][232];
  for (int i = tid; i < 3*4*232; i += 256) {
    const int c = i % 232, r = (i / 232) % 4, cc = i / 928;
    const int y = band*2 - 1 + r, gx = c - 1;
    float v = 0.f;
    if (c < 226 && y >= 0 && y < 224 && gx >= 0 && gx < 224)
      v = spec[((size_t)b*3 + cc) * PIX + (size_t)y * N224 + gx];
    in_t[cc][r][c] = v;
  }
  __syncthreads();
  const int X0 = xh*112 + xq*56 + xs*28;   // 0..196 step 28, 16B-aligned
  float acc[28];
#pragma unroll
  for (int px = 0; px < 28; ++px) acc[px] = 0.f;
#pragma unroll
  for (int cc = 0; cc < 3; ++cc) {
    const float4 w0 = *(const float4*)&wt1[cc*192 + co*12];
    const float4 w1 = *(const float4*)&wt1[cc*192 + co*12 + 4];
    const float  w8 = wt1[cc*192 + co*12 + 8];
    const float wr[9] = {w0.x, w0.y, w0.z, w0.w, w1.x, w1.y, w1.z, w1.w, w8};
#pragma unroll
    for (int ky = 0; ky < 3; ++ky) {
      float xr[32];
      const float4* rp = (const float4*)&in_t[cc][cr + ky][X0];
#pragma unroll
      for (int t = 0; t < 8; ++t) {
        const float4 v = rp[t];
        xr[4*t]=v.x; xr[4*t+1]=v.y; xr[4*t+2]=v.z; xr[4*t+3]=v.w;
      }
#pragma unroll
      for (int px = 0; px < 28; ++px) {
        acc[px] = fmaf(xr[px  ], wr[ky*3  ], acc[px]);
        acc[px] = fmaf(xr[px+1], wr[ky*3+1], acc[px]);
        acc[px] = fmaf(xr[px+2], wr[ky*3+2], acc[px]);
      }
    }
  }
  const float s = su1[co], u = su1[16+co];
  float m[14];
#pragma unroll
  for (int p = 0; p < 14; ++p)
    m[p] = fmaxf(acc[2*p]*s + u, acc[2*p+1]*s + u);
#pragma unroll
  for (int p = 0; p < 14; ++p) {
    const float pm = __shfl_xor(m[p], 16);
    m[p] = fmaxf(fmaxf(m[p], pm), 0.f);
  }
  if (cr == 0) {
    const int pxb = X0 >> 1;
    float* op = &out[(((size_t)b*16 + co)*112 + band)*112 + pxb];
#pragma unroll
    for (int p = 0; p < 14; ++p) op[p] = m[p];
  }
}

// -------- conv2 (16->32)+BN+ReLU+pool: weight prefetch double-buffer --------
// grid (2 xh, 56 pooled-row, 16 b). lane: co=&31, cr=>>5. wave: 14-px slice.
__global__ __launch_bounds__(256) void conv2(
    const float* __restrict__ h1, const float* __restrict__ wt2,
    const float* __restrict__ su2, float* __restrict__ out)
{
  const int xh = blockIdx.x, band = blockIdx.y, b = blockIdx.z;
  const int tid = threadIdx.x;
  const int lane = tid & 63, w = tid >> 6;
  const int co = lane & 31, cr = lane >> 5;
  __shared__ float in_t[16][4][64];
  for (int i = tid; i < 16*4*58; i += 256) {
    const int c = i % 58, r = (i / 58) % 4, cc = i / 232;
    const int y = band*2 - 1 + r, gx = xh*56 - 1 + c;
    float v = 0.f;
    if (y >= 0 && y < 112 && gx >= 0 && gx < 112)
      v = h1[(((size_t)b*16 + cc)*112 + y)*112 + gx];
    in_t[cc][r][c] = v;
  }
  __syncthreads();
  const int X0 = w * 14;                   // 0,14,28,42 — 8B-aligned
  float acc[14];
#pragma unroll
  for (int px = 0; px < 14; ++px) acc[px] = 0.f;
  const float* __restrict__ wp = wt2 + co*12;
  float4 nw0 = *(const float4*)(wp);
  float4 nw1 = *(const float4*)(wp + 4);
  float  nw8 = wp[8];
  for (int cc = 0; cc < 16; ++cc) {
    const float4 w0 = nw0, w1 = nw1; const float w8 = nw8;
    if (cc < 15) {
      const float* np = wp + (cc + 1) * 384;
      nw0 = *(const float4*)(np);
      nw1 = *(const float4*)(np + 4);
      nw8 = np[8];
    }
    const float wr[9] = {w0.x, w0.y, w0.z, w0.w, w1.x, w1.y, w1.z, w1.w, w8};
#pragma unroll
    for (int ky = 0; ky < 3; ++ky) {
      float xr[16];
      const float2* rp = (const float2*)&in_t[cc][cr + ky][X0];
#pragma unroll
      for (int t = 0; t < 8; ++t) {
        const float2 v = rp[t];
        xr[2*t] = v.x; xr[2*t+1] = v.y;
      }
#pragma unroll
      for (int px = 0; px < 14; ++px) {
        acc[px] = fmaf(xr[px  ], wr[ky*3  ], acc[px]);
        acc[px] = fmaf(xr[px+1], wr[ky*3+1], acc[px]);
        acc[px] = fmaf(xr[px+2], wr[ky*3+2], acc[px]);
      }
    }
  }
  const float s = su2[co], u = su2[32+co];
  float m[7];
#pragma unroll
  for (int p = 0; p < 7; ++p)
    m[p] = fmaxf(acc[2*p]*s + u, acc[2*p+1]*s + u);
#pragma unroll
  for (int p = 0; p < 7; ++p) {
    const float pm = __shfl_xor(m[p], 32);
    m[p] = fmaxf(fmaxf(m[p], pm), 0.f);
  }
  if (cr == 0) {
    float* op = &out[(((size_t)b*32 + co)*56 + band)*56 + xh*28 + w*7];
#pragma unroll
    for (int p = 0; p < 7; ++p) op[p] = m[p];
  }
}

// -------- conv3 (32->64)+BN+ReLU+partial mean: weight prefetch --------------
// grid (56 row, 16 b). 256 thr = 64 co x 4 x-slices of 14.
__global__ __launch_bounds__(256) void conv3(
    const float* __restrict__ h2, const float* __restrict__ wt3,
    const float* __restrict__ su3, float* __restrict__ part)
{
  const int band = blockIdx.x, b = blockIdx.y;
  const int tid = threadIdx.x;
  const int co = tid & 63, w = tid >> 6;
  __shared__ float in_t[32][3][64];
  __shared__ float red[4][64];
  for (int i = tid; i < 32*3*58; i += 256) {
    const int c = i % 58, r = (i / 58) % 3, cc = i / 174;
    const int y = band - 1 + r, gx = c - 1;
    float v = 0.f;
    if (y >= 0 && y < 56 && gx >= 0 && gx < 56)
      v = h2[(((size_t)b*32 + cc)*56 + y)*56 + gx];
    in_t[cc][r][c] = v;
  }
  __syncthreads();
  const int X0 = w * 14;
  float acc[14];
#pragma unroll
  for (int px = 0; px < 14; ++px) acc[px] = 0.f;
  const float* __restrict__ wp = wt3 + co*12;
  float4 nw0 = *(const float4*)(wp);
  float4 nw1 = *(const float4*)(wp + 4);
  float  nw8 = wp[8];
  for (int cc = 0; cc < 32; ++cc) {
    const float4 w0 = nw0, w1 = nw1; const float w8 = nw8;
    if (cc < 31) {
      const float* np = wp + (cc + 1) * 768;
      nw0 = *(const float4*)(np);
      nw1 = *(const float4*)(np + 4);
      nw8 = np[8];
    }
    const float wr[9] = {w0.x, w0.y, w0.z, w0.w, w1.x, w1.y, w1.z, w1.w, w8};
#pragma unroll
    for (int rr = 0; rr < 3; ++rr) {
      float xr[16];
      const float2* rp = (const float2*)&in_t[cc][rr][X0];
#pragma unroll
      for (int t = 0; t < 8; ++t) {
        const float2 v = rp[t];
        xr[2*t] = v.x; xr[2*t+1] = v.y;
      }
#pragma unroll
      for (int px = 0; px < 14; ++px) {
        acc[px] = fmaf(xr[px  ], wr[rr*3  ], acc[px]);
        acc[px] = fmaf(xr[px+1], wr[rr*3+1], acc[px]);
        acc[px] = fmaf(xr[px+2], wr[rr*3+2], acc[px]);
      }
    }
  }
  const float s = su3[co], u = su3[64+co];
  float sum = 0.f;
#pragma unroll
  for (int px = 0; px < 14; ++px)
    sum += fmaxf(acc[px]*s + u, 0.f);
  red[w][co] = sum;
  __syncthreads();
  if (tid < 64)
    part[((size_t)b*64 + co)*56 + band] =
        red[0][co] + red[1][co] + red[2][co] + red[3][co];
}

// ------------- global mean (56 partials) + FC + ReLU ------------------------
__global__ __launch_bounds__(128) void mean_fc(
    const float* __restrict__ part, const float* __restrict__ fw,
    const float* __restrict__ fb, float* __restrict__ out)
{
  const int b = blockIdx.x;
  const int tid = threadIdx.x;
  __shared__ float h3s[64];
  if (tid < 64) {
    float s = 0.f;
    const float* pp = part + ((size_t)b*64 + tid)*56;
#pragma unroll
    for (int i = 0; i < 56; ++i) s += pp[i];
    h3s[tid] = s * (1.0f / 3136.0f);
  }
  __syncthreads();
  float acc = fb[tid];
#pragma unroll
  for (int c = 0; c < 64; ++c)
    acc = fmaf(h3s[c], fw[tid*64 + c], acc);
  out[b*128 + tid] = fmaxf(acc, 0.f);
}

extern "C" void kernel_launch(void* const* d_in, const int* in_sizes, int n_in,
                              void* d_out, int out_size, void* d_ws, size_t ws_size,
                              hipStream_t stream) {
  const float* seq  = (const float*)d_in[0];
  const float* dcos = (const float*)d_in[1];
  const float* dsin = (const float*)d_in[2];
  const float* c1w  = (const float*)d_in[3];
  const float* c1b  = (const float*)d_in[4];
  const float* b1g  = (const float*)d_in[5];
  const float* b1b  = (const float*)d_in[6];
  const float* b1m  = (const float*)d_in[7];
  const float* b1v  = (const float*)d_in[8];
  const float* c2w  = (const float*)d_in[9];
  const float* c2b  = (const float*)d_in[10];
  const float* b2g  = (const float*)d_in[11];
  const float* b2b  = (const float*)d_in[12];
  const float* b2m  = (const float*)d_in[13];
  const float* b2v  = (const float*)d_in[14];
  const float* c3w  = (const float*)d_in[15];
  const float* c3b  = (const float*)d_in[16];
  const float* b3g  = (const float*)d_in[17];
  const float* b3b  = (const float*)d_in[18];
  const float* b3m  = (const float*)d_in[19];
  const float* b3v  = (const float*)d_in[20];
  const float* fw   = (const float*)d_in[21];
  const float* fb   = (const float*)d_in[22];
  float* out = (float*)d_out;

  float* ws   = (float*)d_ws;
  float* Cx   = ws;                   // 1,214,976 (113 rows x 224, 48 imgs)
  float* Sx   = ws + OFF_SX;          // 1,214,976
  float* spec = ws + OFF_SPEC;        // 2,408,448
  float* h1   = ws;                   // 3,211,264 (reuses dead Cx/Sx)
  float* h2   = ws + OFF_SPEC;        // 1,605,632 (reuses dead spec)
  float* wt3  = ws + OFF_WT;
  float* wt2  = ws + OFF_WT2;
  float* wt1  = ws + OFF_WT1;
  float* su3  = ws + OFF_SU3;
  float* su2  = ws + OFF_SU2;
  float* su1  = ws + OFF_SU1;
  float* part = ws + OFF_PART;        // 57,344

  prep<<<24, 256, 0, stream>>>(c1w, c2w, c3w, c1b, c2b, c3b,
                               b1g, b1b, b1m, b1v, b2g, b2b, b2m, b2v,
                               b3g, b3b, b3m, b3v, wt3, wt2, wt1, su3, su2, su1);
  dft1<<<dim3(7, 4, 48), 256, 0, stream>>>(seq, dcos, dsin, Cx, Sx);
  dft2<<<dim3(4, 4, 48), 256, 0, stream>>>(Cx, Sx, dcos, dsin, spec);
  conv1<<<dim3(112, 16), 256, 0, stream>>>(spec, wt1, su1, h1);
  conv2<<<dim3(2, 56, 16), 256, 0, stream>>>(h1, wt2, su2, h2);
  conv3<<<dim3(56, 16), 256, 0, stream>>>(h2, wt3, su3, part);
  mean_fc<<<16, 128, 0, stream>>>(part, fw, fb, out);
}